// Round 1
// baseline (207.909 us; speedup 1.0000x reference)
//
#include <hip/hip_runtime.h>

// Sigmoid-attention: O = sigmoid(Q K^T / sqrt(64)) V, per (b,h). B*H=64, S=2048, D=64.
// Strategy: bf16 MFMA (16x16x32), flash-style K-loop, NO online softmax needed
// (sigmoid is elementwise). Q pre-scaled by -log2(e)/8 so p = rcp(1+exp2(score)).

typedef __bf16 bf16_t;
typedef __attribute__((ext_vector_type(8))) __bf16 bf16x8;
typedef __attribute__((ext_vector_type(4))) __bf16 bf16x4;
typedef __attribute__((ext_vector_type(4))) float  f32x4;

#if __has_builtin(__builtin_amdgcn_exp2f)
#define FAST_EXP2(x) __builtin_amdgcn_exp2f(x)
#else
#define FAST_EXP2(x) exp2f(x)
#endif
#if __has_builtin(__builtin_amdgcn_rcpf)
#define FAST_RCP(x) __builtin_amdgcn_rcpf(x)
#else
#define FAST_RCP(x) (1.0f / (x))
#endif

static constexpr int SEQ = 2048;
static constexpr int DH  = 64;
static constexpr int KB  = 32;          // keys per k-iteration
static constexpr int NIT = SEQ / KB;    // 64
static constexpr int QPW = 64;          // q rows per wave
static constexpr int QPB = 256;         // q rows per block (4 waves)

__global__ __launch_bounds__(256, 2)
void sigattn_kernel(const float* __restrict__ Qg, const float* __restrict__ Kg,
                    const float* __restrict__ Vg, float* __restrict__ Og)
{
    // Frag-major LDS: frag f, lane l, 8 contiguous bf16 at [(f*64+l)*8].
    __shared__ bf16_t Kbuf[2][4 * 64 * 8];   // 4 frags = (ksub 2) x (dhalf 2)
    __shared__ bf16_t Vbuf[2][4 * 64 * 8];   // 4 frags = dtile 0..3
    __shared__ bf16_t Pbuf[4][QPW * KB];     // per-wave 64q x 32k, frag-major

    const int t    = threadIdx.x;
    const int wave = t >> 6;
    const int lane = t & 63;
    const int c16  = lane & 15;
    const int g4   = lane >> 4;

    const int bh    = blockIdx.x;   // 0..63  (same-head blocks -> same XCD)
    const int qtile = blockIdx.y;   // 0..7

    const size_t hbase = (size_t)bh * SEQ * DH;
    const float* Qp = Qg + hbase;
    const float* Kp = Kg + hbase;
    const float* Vp = Vg + hbase;
    float*       Op = Og + hbase;

    const int qwave = qtile * QPB + wave * QPW;

    // ---- Q fragments (held in regs, pre-scaled by -log2(e)/sqrt(D)) ----
    // B-frag(Q, qs, dh): lane holds Q[qwave + qs*16 + c16][dh*32 + g4*8 + j]
    const float qscale = -0.125f * 1.44269504088896340736f;
    bf16x8 qf[4][2];
    #pragma unroll
    for (int qs = 0; qs < 4; ++qs) {
        #pragma unroll
        for (int dh = 0; dh < 2; ++dh) {
            const float* p = Qp + (size_t)(qwave + qs * 16 + c16) * DH + dh * 32 + g4 * 8;
            f32x4 a = *(const f32x4*)p;
            f32x4 b = *(const f32x4*)(p + 4);
            bf16x8 f;
            f[0] = (bf16_t)(a.x * qscale); f[1] = (bf16_t)(a.y * qscale);
            f[2] = (bf16_t)(a.z * qscale); f[3] = (bf16_t)(a.w * qscale);
            f[4] = (bf16_t)(b.x * qscale); f[5] = (bf16_t)(b.y * qscale);
            f[6] = (bf16_t)(b.z * qscale); f[7] = (bf16_t)(b.w * qscale);
            qf[qs][dh] = f;
        }
    }

    // ---- staging: thread t fills frag element block t (b128 at Kbuf+t*16B) ----
    // K frag fid = wave = ks*2+dh: value K[kb + ks*16 + c16][dh*32 + g4*8 + j]
    // V frag fid = wave = dtile  : value V[kb + g4*8 + j][dtile*16 + c16]
    const int sks = wave >> 1;
    const int sdh = wave & 1;

    f32x4 kst0, kst1;
    float vst[8];
    auto issue_loads = [&](int kb0) {
        const float* pk = Kp + (size_t)(kb0 + sks * 16 + c16) * DH + sdh * 32 + g4 * 8;
        kst0 = *(const f32x4*)pk;
        kst1 = *(const f32x4*)(pk + 4);
        const float* pv = Vp + (size_t)(kb0 + g4 * 8) * DH + wave * 16 + c16;
        #pragma unroll
        for (int j = 0; j < 8; ++j) vst[j] = pv[(size_t)j * DH];
    };
    auto store_lds = [&](int buf) {
        bf16x8 k8;
        k8[0] = (bf16_t)kst0.x; k8[1] = (bf16_t)kst0.y; k8[2] = (bf16_t)kst0.z; k8[3] = (bf16_t)kst0.w;
        k8[4] = (bf16_t)kst1.x; k8[5] = (bf16_t)kst1.y; k8[6] = (bf16_t)kst1.z; k8[7] = (bf16_t)kst1.w;
        *(bf16x8*)&Kbuf[buf][t * 8] = k8;
        bf16x8 v8;
        #pragma unroll
        for (int j = 0; j < 8; ++j) v8[j] = (bf16_t)vst[j];
        *(bf16x8*)&Vbuf[buf][t * 8] = v8;
    };

    issue_loads(0);
    store_lds(0);

    f32x4 acc[4][4] = {};   // [qs][dtile], C-layout: row=q (g4*4+r), col=d (c16)

    for (int it = 0; it < NIT; ++it) {
        const int buf = it & 1;
        __syncthreads();                       // publishes buf
        if (it + 1 < NIT) issue_loads((it + 1) * KB);   // prefetch next tile (global->regs)

        bf16x8 kf[4], vf[4];
        #pragma unroll
        for (int f = 0; f < 4; ++f) kf[f] = *(const bf16x8*)&Kbuf[buf][(f * 64 + lane) * 8];
        #pragma unroll
        for (int f = 0; f < 4; ++f) vf[f] = *(const bf16x8*)&Vbuf[buf][(f * 64 + lane) * 8];

        // S^T = K * Q^T per (qs, ks): C row = key (ks*16 + g4*4 + r), col = q (qs*16 + c16).
        // Lane's 4 regs = 4 consecutive keys -> sigmoid -> pack b64 straight into
        // PV A-frag-major layout in Pbuf.
        #pragma unroll
        for (int qs = 0; qs < 4; ++qs) {
            #pragma unroll
            for (int ks = 0; ks < 2; ++ks) {
                f32x4 s = {0.f, 0.f, 0.f, 0.f};
                s = __builtin_amdgcn_mfma_f32_16x16x32_bf16(kf[ks * 2 + 0], qf[qs][0], s, 0, 0, 0);
                s = __builtin_amdgcn_mfma_f32_16x16x32_bf16(kf[ks * 2 + 1], qf[qs][1], s, 0, 0, 0);
                bf16x4 p4;
                #pragma unroll
                for (int r = 0; r < 4; ++r)
                    p4[r] = (bf16_t)FAST_RCP(1.0f + FAST_EXP2(s[r]));
                // element P[q][k], q=qs*16+c16, k=ks*16+g4*4+r  ->
                // Pbuf[(qs*64 + (k>>3)*16 + (q&15))*8 + (k&7)]
                *(bf16x4*)&Pbuf[wave][(qs * 64 + (ks * 2 + (g4 >> 1)) * 16 + c16) * 8 + (g4 & 1) * 4] = p4;
            }
        }

        // same-wave LDS write->read ordering (no block barrier needed: Pbuf is per-wave)
        asm volatile("s_waitcnt lgkmcnt(0)" ::: "memory");

        // O[qs][dt] += P * V
        #pragma unroll
        for (int qs = 0; qs < 4; ++qs) {
            bf16x8 pf = *(const bf16x8*)&Pbuf[wave][(qs * 64 + lane) * 8];
            #pragma unroll
            for (int dt = 0; dt < 4; ++dt)
                acc[qs][dt] = __builtin_amdgcn_mfma_f32_16x16x32_bf16(pf, vf[dt], acc[qs][dt], 0, 0, 0);
        }

        if (it + 1 < NIT) store_lds(buf ^ 1);   // write next tile into other buffer
    }

    // ---- epilogue: C-layout -> global fp32 ----
    #pragma unroll
    for (int qs = 0; qs < 4; ++qs) {
        const int q0 = qwave + qs * 16 + g4 * 4;
        #pragma unroll
        for (int r = 0; r < 4; ++r) {
            float* po = Op + (size_t)(q0 + r) * DH + c16;
            po[0]  = acc[qs][0][r];
            po[16] = acc[qs][1][r];
            po[32] = acc[qs][2][r];
            po[48] = acc[qs][3][r];
        }
    }
}

extern "C" void kernel_launch(void* const* d_in, const int* in_sizes, int n_in,
                              void* d_out, int out_size, void* d_ws, size_t ws_size,
                              hipStream_t stream)
{
    const float* q = (const float*)d_in[0];
    const float* k = (const float*)d_in[1];
    const float* v = (const float*)d_in[2];
    float* o = (float*)d_out;
    dim3 grid(64, SEQ / QPB);   // (bh, qtile) -> same-head blocks share an XCD
    sigattn_kernel<<<grid, dim3(256), 0, stream>>>(q, k, v, o);
}